// Round 11
// baseline (17585.616 us; speedup 1.0000x reference)
//
#include <hip/hip_runtime.h>

#define TT 4096

typedef __attribute__((ext_vector_type(2))) unsigned int u2v;
typedef __attribute__((ext_vector_type(4))) unsigned int u4v;
typedef __attribute__((ext_vector_type(2))) __fp16 f16x2;
typedef __attribute__((ext_vector_type(2))) _Float16 F16x2;
union HU { unsigned int u; f16x2 hf; F16x2 hF; };

// ws layout (float offsets):
//   M    @ 0      : 2048*64 = 131072   (W_in @ C)
//   wtil @ 131072 : 64                 (C^T @ dense_W[:64])
//   yp   @ 131200 : 4096*64 = 262144   (per-WG dense sums via atomicAdd)
//   hpub @ 393344 : 2 slots * 1024 packets * (u32 data, u32 tag)
// hpub needs NO init: ws poisoned 0xAA -> tag never matches.

__global__ void esn_prep(const float* __restrict__ C,
                         const float* __restrict__ Win,
                         const float* __restrict__ dW,
                         float* __restrict__ M,
                         float* __restrict__ wtil,
                         float* __restrict__ yp) {
  __shared__ float s[64];
  const int b = blockIdx.x, i = threadIdx.x;
  if (b < 2048) {
    s[i] = Win[b * 64 + i];
    __syncthreads();
    float acc = 0.f;
#pragma unroll 16
    for (int d = 0; d < 64; ++d) acc += s[d] * C[d * 64 + i];
    M[b * 64 + i] = acc;
  } else if (b == 2048) {
    s[i] = dW[i];
    __syncthreads();
    float acc = 0.f;
    for (int d = 0; d < 64; ++d) acc += s[d] * C[d * 64 + i];
    wtil[i] = acc;
  } else {
    yp[(b - 2049) * 64 + i] = 0.f;  // atomicAdd targets
  }
}

// Call-free tanh: tanh(x) = 1 - 2/(exp(2x)+1)
__device__ __forceinline__ float fast_tanh(float x) {
  const float e = __builtin_amdgcn_exp2f(x * 2.8853900817779268f);
  return 1.0f - 2.0f * __builtin_amdgcn_rcpf(e + 1.0f);
}

__device__ __forceinline__ float fd(unsigned wa, unsigned ha, float c) {
  HU A, B; A.u = wa; B.u = ha;
#if __has_builtin(__builtin_amdgcn_fdot2)
  return __builtin_amdgcn_fdot2(A.hF, B.hF, c, false);
#else
  return c + (float)A.hf.x * (float)B.hf.x + (float)A.hf.y * (float)B.hf.y;
#endif
}

// 64 WGs x 1024 threads, wave-specialized, ZERO per-step barriers.
//  waves 0-7 : compute 4 rows each; consume h chunk-pairs gated by LDS flags
//  wave 15   : sole poller (R9/R10 lesson: one poller wave per WG).
//              8 chunks x 128 packets; done-mask sweep; per-chunk flag release
//              the moment its 64 lanes' tags match -> compute overlaps detect.
//  waves 8-14: exit after W staging.
// Flags are step-tagged (monotonic -> no reset, no ABA); shh double-buffered
// by parity; producers publish (data,tag,data,tag) dwordx4 immediately.
__global__ __launch_bounds__(1024) void esn_recur(
    const float* __restrict__ X, const float* __restrict__ M,
    const float* __restrict__ W, const float* __restrict__ dW,
    unsigned int* __restrict__ hpub, float* __restrict__ yp) {
  extern __shared__ unsigned int smem[];
  unsigned int* w16 = smem;           // 32 rows x 1024 u32 (fp16 pairs)
  unsigned int* shh = smem + 32768;   // 2 x 1024 u32 (double-buffered h)
  unsigned int* flg = smem + 34816;   // 8 step-tagged chunk flags
  const int tid = threadIdx.x;
  const int lane = tid & 63;
  const int wave = tid >> 6;
  const int b = blockIdx.x;
  // one-time: stage 32 rows of W into LDS as packed fp16 (all 16 waves)
  for (int i = tid; i < 32768; i += 1024) {
    const int r = i >> 10, j = i & 1023;
    const float2 w2 = *(const float2*)(W + (size_t)(b * 32 + r) * 2048 + 2 * j);
    HU hu; hu.hf = __builtin_amdgcn_cvt_pkrtz(w2.x, w2.y);
    w16[i] = hu.u;
  }
  shh[1024 + tid] = 0u;          // slot 1 = h_{-1} = 0 (read at t=0)
  if (tid < 8) flg[tid] = 0u;    // "chunk ready for step 0"
  __syncthreads();

  if (wave >= 8 && wave != 15) return;

  if (wave == 15) {
    // ---------------- poller ----------------
    for (int t = 0; t < TT - 1; ++t) {
      const unsigned tg = (unsigned)t + 1u;
      const unsigned int* slot = hpub + ((t & 1) << 11);
      unsigned int* sh = shh + ((t & 1) << 10);
      const unsigned int* p0 = slot + 4 * lane;         // chunks 0-3
      const unsigned int* p1 = slot + 1024 + 4 * lane;  // chunks 4-7
      unsigned done = 0u;
      while (done != 0xFFu) {
        u4v q0, q1, q2, q3, q4, q5, q6, q7;
        asm volatile(
            "global_load_dwordx4 %0, %8, off sc0 sc1\n\t"
            "global_load_dwordx4 %1, %8, off offset:1024 sc0 sc1\n\t"
            "global_load_dwordx4 %2, %8, off offset:2048 sc0 sc1\n\t"
            "global_load_dwordx4 %3, %8, off offset:3072 sc0 sc1\n\t"
            "global_load_dwordx4 %4, %9, off sc0 sc1\n\t"
            "global_load_dwordx4 %5, %9, off offset:1024 sc0 sc1\n\t"
            "global_load_dwordx4 %6, %9, off offset:2048 sc0 sc1\n\t"
            "global_load_dwordx4 %7, %9, off offset:3072 sc0 sc1\n\t"
            "s_waitcnt vmcnt(0)"
            : "=&v"(q0), "=&v"(q1), "=&v"(q2), "=&v"(q3),
              "=&v"(q4), "=&v"(q5), "=&v"(q6), "=&v"(q7)
            : "v"(p0), "v"(p1)
            : "memory");
        const unsigned before = done;
#define PROC(c, Q)                                                          \
        if (!(done & (1u << c)) && __all((Q).y == tg && (Q).w == tg)) {     \
          *(uint2*)(sh + 128 * c + 2 * lane) = make_uint2((Q).x, (Q).z);    \
          __hip_atomic_store(&flg[c], tg, __ATOMIC_RELEASE,                 \
                             __HIP_MEMORY_SCOPE_WORKGROUP);                 \
          done |= 1u << c;                                                  \
        }
        PROC(0, q0) PROC(1, q1) PROC(2, q2) PROC(3, q3)
        PROC(4, q4) PROC(5, q5) PROC(6, q6) PROC(7, q7)
#undef PROC
        if (done == before && done != 0xFFu) __builtin_amdgcn_s_sleep(1);
      }
    }
    return;
  }

  // ---------------- compute waves 0-7: 4 rows each ----------------
  const int r0 = b * 32 + wave * 4;
  const float m0 = M[r0 * 64 + lane];
  const float m1 = M[(r0 + 1) * 64 + lane];
  const float m2 = M[(r0 + 2) * 64 + lane];
  const float m3 = M[(r0 + 3) * 64 + lane];
  const float dw0 = dW[64 + r0], dw1 = dW[64 + r0 + 1];
  const float dw2 = dW[64 + r0 + 2], dw3 = dW[64 + r0 + 3];
  const unsigned int* wr0 = w16 + ((wave * 4) << 10);
  const unsigned int* wr1 = wr0 + 1024;
  const unsigned int* wr2 = wr0 + 2048;
  const unsigned int* wr3 = wr0 + 3072;

  for (int t = 0; t < TT; ++t) {
    const float xv = X[t * 64 + lane];
    const unsigned need = (unsigned)t;  // flags carry step tag t (set at t-1)
    const unsigned int* sh = shh + (((t + 1) & 1) << 10);
    float a0 = m0 * xv, a1 = m1 * xv, a2 = m2 * xv, a3 = m3 * xv;
#pragma unroll
    for (int k = 0; k < 4; ++k) {   // super-chunk = chunks 2k, 2k+1 (b128)
      while (__hip_atomic_load(&flg[2 * k], __ATOMIC_ACQUIRE,
                               __HIP_MEMORY_SCOPE_WORKGROUP) < need) {}
      while (__hip_atomic_load(&flg[2 * k + 1], __ATOMIC_ACQUIRE,
                               __HIP_MEMORY_SCOPE_WORKGROUP) < need) {}
      const int o = 256 * k + 4 * lane;
      const u4v hq = *(const u4v*)(sh + o);
      const u4v wq0 = *(const u4v*)(wr0 + o);
      const u4v wq1 = *(const u4v*)(wr1 + o);
      const u4v wq2 = *(const u4v*)(wr2 + o);
      const u4v wq3 = *(const u4v*)(wr3 + o);
#pragma unroll
      for (int j = 0; j < 4; ++j) {
        a0 = fd(wq0[j], hq[j], a0);
        a1 = fd(wq1[j], hq[j], a1);
        a2 = fd(wq2[j], hq[j], a2);
        a3 = fd(wq3[j], hq[j], a3);
      }
    }
#pragma unroll
    for (int off = 32; off; off >>= 1) {
      a0 += __shfl_xor(a0, off, 64);
      a1 += __shfl_xor(a1, off, 64);
      a2 += __shfl_xor(a2, off, 64);
      a3 += __shfl_xor(a3, off, 64);
    }
    if (lane == 0) {
      const float h0 = fast_tanh(a0);
      const float h1 = fast_tanh(a1);
      const float h2 = fast_tanh(a2);
      const float h3 = fast_tanh(a3);
      if (t + 1 < TT) {
        HU pk0, pk1;
        pk0.hf = __builtin_amdgcn_cvt_pkrtz(h0, h1);
        pk1.hf = __builtin_amdgcn_cvt_pkrtz(h2, h3);
        const unsigned tg = (unsigned)t + 1u;
        u4v pv; pv.x = pk0.u; pv.y = tg; pv.z = pk1.u; pv.w = tg;
        unsigned int* dst = hpub + ((t & 1) << 11) + 32 * b + 4 * wave;
        asm volatile("global_store_dwordx4 %0, %1, off sc0 sc1"
                     :: "v"(dst), "v"(pv) : "memory");
      }
      atomicAdd(&yp[t * 64 + b], dw0 * h0 + dw1 * h1 + dw2 * h2 + dw3 * h3);
    }
  }
}

__global__ void esn_out(const float* __restrict__ X,
                        const float* __restrict__ wtil,
                        const float* __restrict__ yp,
                        const float* __restrict__ bptr,
                        float* __restrict__ out) {
  const int tid = threadIdx.x;
  const int lane = tid & 63;
  const int wave = tid >> 6;
  const int t = blockIdx.x * 4 + wave;
  float v = wtil[lane] * X[t * 64 + lane] + yp[t * 64 + lane];
#pragma unroll
  for (int off = 32; off; off >>= 1) v += __shfl_xor(v, off, 64);
  if (lane == 0) out[t] = v + bptr[0];
}

#define ESN_LDS_BYTES 139296  // (32768 + 2048 + 8) * 4

struct EsnInit {
  EsnInit() {
    (void)hipFuncSetAttribute(reinterpret_cast<const void*>(&esn_recur),
                              hipFuncAttributeMaxDynamicSharedMemorySize,
                              ESN_LDS_BYTES);
  }
};
static EsnInit g_esn_init;

extern "C" void kernel_launch(void* const* d_in, const int* in_sizes, int n_in,
                              void* d_out, int out_size, void* d_ws, size_t ws_size,
                              hipStream_t stream) {
  const float* X   = (const float*)d_in[0];
  const float* C   = (const float*)d_in[1];
  const float* Win = (const float*)d_in[2];
  const float* W   = (const float*)d_in[3];
  const float* dW  = (const float*)d_in[4];
  const float* db  = (const float*)d_in[5];
  float* ws   = (float*)d_ws;
  float* M    = ws;
  float* wtil = ws + 131072;
  float* yp   = ws + 131200;
  unsigned int* hpub = (unsigned int*)(ws + 393344);

  // 2048 M-blocks + 1 wtil + 4096 yp-zero blocks
  esn_prep<<<6145, 64, 0, stream>>>(C, Win, dW, M, wtil, yp);

  void* args[] = {(void*)&X, (void*)&M, (void*)&W, (void*)&dW,
                  (void*)&hpub, (void*)&yp};
  (void)hipLaunchCooperativeKernel(reinterpret_cast<void*>(&esn_recur), dim3(64),
                                   dim3(1024), args, ESN_LDS_BYTES, stream);

  esn_out<<<1024, 256, 0, stream>>>(X, wtil, yp, db, (float*)d_out);
}

// Round 12
// 15300.246 us; speedup vs baseline: 1.1494x; 1.1494x over previous
//
#include <hip/hip_runtime.h>

#define TT 4096

typedef __attribute__((ext_vector_type(2))) unsigned int u2v;
typedef __attribute__((ext_vector_type(4))) unsigned int u4v;
typedef __attribute__((ext_vector_type(2))) __fp16 f16x2;
typedef __attribute__((ext_vector_type(2))) _Float16 F16x2;
union HU { unsigned int u; f16x2 hf; F16x2 hF; };

// ws layout (float offsets):
//   M    @ 0      : 2048*64 = 131072  (W_in @ C)
//   wtil @ 131072 : 64                (C^T @ dense_W[:64])
//   yp   @ 131200 : 4096              (full dense h-dot per step, WG0 wave5)
//   dWp  @ 135296 : 1024 u32          (dense_W[64:2112] packed fp16 pairs)
//   hpub @ 136320 : 2 slots * 1024 packets * (u32 data, u32 tag)
// hpub needs NO init: ws poisoned 0xAA -> tag never matches 1..TT.

__global__ void esn_prep(const float* __restrict__ C,
                         const float* __restrict__ Win,
                         const float* __restrict__ dW,
                         float* __restrict__ M,
                         float* __restrict__ wtil,
                         unsigned int* __restrict__ dWp) {
  __shared__ float s[64];
  const int b = blockIdx.x, i = threadIdx.x;
  if (b < 2048) {
    s[i] = Win[b * 64 + i];
    __syncthreads();
    float acc = 0.f;
#pragma unroll 16
    for (int d = 0; d < 64; ++d) acc += s[d] * C[d * 64 + i];
    M[b * 64 + i] = acc;
  } else if (b == 2048) {
    s[i] = dW[i];
    __syncthreads();
    float acc = 0.f;
    for (int d = 0; d < 64; ++d) acc += s[d] * C[d * 64 + i];
    wtil[i] = acc;
  } else {
    const int idx = (b - 2049) * 64 + i;  // 0..1023
    HU hu;
    hu.hf = __builtin_amdgcn_cvt_pkrtz(dW[64 + 2 * idx], dW[64 + 2 * idx + 1]);
    dWp[idx] = hu.u;
  }
}

// Call-free tanh: tanh(x) = 1 - 2/(exp(2x)+1)
__device__ __forceinline__ float fast_tanh(float x) {
  const float e = __builtin_amdgcn_exp2f(x * 2.8853900817779268f);
  return 1.0f - 2.0f * __builtin_amdgcn_rcpf(e + 1.0f);
}

__device__ __forceinline__ float fd(unsigned wa, unsigned ha, float c) {
  HU A, B; A.u = wa; B.u = ha;
#if __has_builtin(__builtin_amdgcn_fdot2)
  return __builtin_amdgcn_fdot2(A.hF, B.hF, c, false);
#else
  return c + (float)A.hf.x * (float)B.hf.x + (float)A.hf.y * (float)B.hf.y;
#endif
}

// 256 WGs x 384 threads (ALL 256 CUs -> LDS stream/CU/step = 48 KB, 4x less
// than R9's 64-CU layout). Waves 0-3: 2 rows each; wave 4: sole poller with
// 4-chunk progressive release (chunk == compute j-iteration); wave 5 (WG0
// only): full dense h-dot -> yp[t]. Zero per-step barriers: double-buffered
// shh by parity + monotone step-tagged LDS flags. h_s lives in shh slot s&1.
__global__ __launch_bounds__(384) void esn_recur(
    const float* __restrict__ X, const float* __restrict__ M,
    const float* __restrict__ W, const unsigned int* __restrict__ dWp,
    unsigned int* __restrict__ hpub, float* __restrict__ yp) {
  __shared__ unsigned int w16[8192];  // 8 rows x 1024 fp16-pair u32
  __shared__ unsigned int shh[2048];  // 2 x 1024 (double-buffered h)
  __shared__ unsigned int flg[4];     // step-tagged chunk flags
  __shared__ int yprog;               // wave5 progress (WG0 back-pressure)
  const int tid = threadIdx.x;
  const int lane = tid & 63;
  const int wave = tid >> 6;
  const int b = blockIdx.x;
  // one-time: stage 8 rows of W as packed fp16
  for (int i = tid; i < 8192; i += 384) {
    const int r = i >> 10, j = i & 1023;
    const float2 w2 = *(const float2*)(W + (size_t)(b * 8 + r) * 2048 + 2 * j);
    HU hu; hu.hf = __builtin_amdgcn_cvt_pkrtz(w2.x, w2.y);
    w16[i] = hu.u;
  }
  for (int k = tid; k < 1024; k += 384) shh[1024 + k] = 0u;  // h_{-1}=0 (slot 1)
  if (tid < 4) flg[tid] = 0u;
  if (tid == 4) yprog = 0;
  __syncthreads();

  if (wave < 4) {
    // ---------------- compute: 2 rows per wave ----------------
    const int r0 = b * 8 + 2 * wave;
    const float m0 = M[r0 * 64 + lane];
    const float m1 = M[(r0 + 1) * 64 + lane];
    const unsigned int* wr0 = w16 + ((2 * wave) << 10);
    const unsigned int* wr1 = wr0 + 1024;
    for (int t = 0; t < TT; ++t) {
      const float xv = X[t * 64 + lane];
      const unsigned int* shr = shh + (((t + 1) & 1) << 10);  // h_{t-1}
      float a0 = m0 * xv, a1 = m1 * xv;
#pragma unroll
      for (int j = 0; j < 4; ++j) {
        while (__hip_atomic_load(&flg[j], __ATOMIC_ACQUIRE,
                                 __HIP_MEMORY_SCOPE_WORKGROUP) < (unsigned)t) {}
        const int o = 256 * j + 4 * lane;
        const u4v hq = *(const u4v*)(shr + o);
        const u4v wq0 = *(const u4v*)(wr0 + o);
        const u4v wq1 = *(const u4v*)(wr1 + o);
#pragma unroll
        for (int k2 = 0; k2 < 4; ++k2) {
          a0 = fd(wq0[k2], hq[k2], a0);
          a1 = fd(wq1[k2], hq[k2], a1);
        }
      }
#pragma unroll
      for (int off = 32; off; off >>= 1) {
        a0 += __shfl_xor(a0, off, 64);
        a1 += __shfl_xor(a1, off, 64);
      }
      if (lane == 0) {
        const float h0 = fast_tanh(a0);
        const float h1 = fast_tanh(a1);
        HU pk; pk.hf = __builtin_amdgcn_cvt_pkrtz(h0, h1);
        u2v pv; pv.x = pk.u; pv.y = (unsigned)t + 1u;
        unsigned int* dst = hpub + ((t & 1) << 11) + 2 * (4 * b + wave);
        asm volatile("global_store_dwordx2 %0, %1, off sc0 sc1"
                     :: "v"(dst), "v"(pv) : "memory");
      }
    }
  } else if (wave == 4) {
    // ---------------- poller ----------------
    for (int tg = 1; tg <= TT; ++tg) {
      if (b == 0 && tg > 3) {  // don't overwrite h chunks wave5 still reads
        while (__hip_atomic_load(&yprog, __ATOMIC_ACQUIRE,
                                 __HIP_MEMORY_SCOPE_WORKGROUP) < tg - 3) {
          __builtin_amdgcn_s_sleep(1);
        }
      }
      const unsigned tgu = (unsigned)tg;
      const unsigned int* slot = hpub + (((tg - 1) & 1) << 11);
      unsigned int* dsh = shh + (((tg - 1) & 1) << 10);
      const unsigned int* p0 = slot + 8 * lane;          // chunks 0,1
      const unsigned int* p1 = slot + 1024 + 8 * lane;   // chunks 2,3
      unsigned done = 0u;
#define COMMIT(c, qa, qb)                                                   \
      if (!((done >> (c)) & 1u) &&                                          \
          __all((qa).y == tgu && (qa).w == tgu &&                           \
                (qb).y == tgu && (qb).w == tgu)) {                          \
        u4v wv; wv.x = (qa).x; wv.y = (qa).z; wv.z = (qb).x; wv.w = (qb).z; \
        *(u4v*)(dsh + 256 * (c) + 4 * lane) = wv;                           \
        if (lane == 0)                                                      \
          __hip_atomic_store(&flg[c], tgu, __ATOMIC_RELEASE,                \
                             __HIP_MEMORY_SCOPE_WORKGROUP);                 \
        done |= 1u << (c);                                                  \
      }
      {  // first sweep: all 4 chunks in one vmcnt window
        u4v q0, q1, q2, q3, q4, q5, q6, q7;
        asm volatile(
            "global_load_dwordx4 %0, %8, off sc0 sc1\n\t"
            "global_load_dwordx4 %1, %8, off offset:16 sc0 sc1\n\t"
            "global_load_dwordx4 %2, %8, off offset:2048 sc0 sc1\n\t"
            "global_load_dwordx4 %3, %8, off offset:2064 sc0 sc1\n\t"
            "global_load_dwordx4 %4, %9, off sc0 sc1\n\t"
            "global_load_dwordx4 %5, %9, off offset:16 sc0 sc1\n\t"
            "global_load_dwordx4 %6, %9, off offset:2048 sc0 sc1\n\t"
            "global_load_dwordx4 %7, %9, off offset:2064 sc0 sc1\n\t"
            "s_waitcnt vmcnt(0)"
            : "=&v"(q0), "=&v"(q1), "=&v"(q2), "=&v"(q3),
              "=&v"(q4), "=&v"(q5), "=&v"(q6), "=&v"(q7)
            : "v"(p0), "v"(p1)
            : "memory");
        COMMIT(0, q0, q1) COMMIT(1, q2, q3) COMMIT(2, q4, q5) COMMIT(3, q6, q7)
      }
      while (done != 0xFu) {  // retries: only missing chunks (poll-volume cap)
        __builtin_amdgcn_s_sleep(1);
#pragma unroll
        for (int c = 0; c < 4; ++c) {
          if (!((done >> c) & 1u)) {
            const unsigned int* pc = p0 + 512 * c;
            u4v qa, qb;
            asm volatile(
                "global_load_dwordx4 %0, %2, off sc0 sc1\n\t"
                "global_load_dwordx4 %1, %2, off offset:16 sc0 sc1\n\t"
                "s_waitcnt vmcnt(0)"
                : "=&v"(qa), "=&v"(qb) : "v"(pc) : "memory");
            COMMIT(c, qa, qb)
          }
        }
      }
#undef COMMIT
    }
  } else {
    // ---------------- wave 5, WG0 only: dense readout ----------------
    if (b != 0) return;
    for (int t = 0; t < TT; ++t) {
      const unsigned int* src = shh + ((t & 1) << 10);  // h_t
      float acc = 0.f;
#pragma unroll
      for (int j = 0; j < 4; ++j) {
        while (__hip_atomic_load(&flg[j], __ATOMIC_ACQUIRE,
                                 __HIP_MEMORY_SCOPE_WORKGROUP) <
               (unsigned)(t + 1)) {
          __builtin_amdgcn_s_sleep(1);
        }
        const int o = 256 * j + 4 * lane;
        const u4v hq = *(const u4v*)(src + o);
        const u4v dq = *(const u4v*)(dWp + o);
#pragma unroll
        for (int k2 = 0; k2 < 4; ++k2) acc = fd(dq[k2], hq[k2], acc);
      }
#pragma unroll
      for (int off = 32; off; off >>= 1) acc += __shfl_xor(acc, off, 64);
      if (lane == 0) yp[t] = acc;
      if (lane == 0)
        __hip_atomic_store(&yprog, t, __ATOMIC_RELEASE,
                           __HIP_MEMORY_SCOPE_WORKGROUP);
    }
  }
}

__global__ void esn_out(const float* __restrict__ X,
                        const float* __restrict__ wtil,
                        const float* __restrict__ yp,
                        const float* __restrict__ bptr,
                        float* __restrict__ out) {
  const int tid = threadIdx.x;
  const int lane = tid & 63;
  const int wave = tid >> 6;
  const int t = blockIdx.x * 4 + wave;
  float v = wtil[lane] * X[t * 64 + lane];
#pragma unroll
  for (int off = 32; off; off >>= 1) v += __shfl_xor(v, off, 64);
  if (lane == 0) out[t] = v + yp[t] + bptr[0];
}

extern "C" void kernel_launch(void* const* d_in, const int* in_sizes, int n_in,
                              void* d_out, int out_size, void* d_ws, size_t ws_size,
                              hipStream_t stream) {
  const float* X   = (const float*)d_in[0];
  const float* C   = (const float*)d_in[1];
  const float* Win = (const float*)d_in[2];
  const float* W   = (const float*)d_in[3];
  const float* dW  = (const float*)d_in[4];
  const float* db  = (const float*)d_in[5];
  float* ws   = (float*)d_ws;
  float* M    = ws;
  float* wtil = ws + 131072;
  float* yp   = ws + 131200;
  unsigned int* dWp  = (unsigned int*)(ws + 135296);
  unsigned int* hpub = (unsigned int*)(ws + 136320);

  // 2048 M-blocks + wtil + 16 dWp-pack blocks
  esn_prep<<<2065, 64, 0, stream>>>(C, Win, dW, M, wtil, dWp);

  void* args[] = {(void*)&X, (void*)&M, (void*)&W, (void*)&dWp,
                  (void*)&hpub, (void*)&yp};
  (void)hipLaunchCooperativeKernel(reinterpret_cast<void*>(&esn_recur),
                                   dim3(256), dim3(384), args, 0, stream);

  esn_out<<<1024, 256, 0, stream>>>(X, wtil, yp, db, (float*)d_out);
}

// Round 14
// 14487.314 us; speedup vs baseline: 1.2139x; 1.0561x over previous
//
#include <hip/hip_runtime.h>

#define TT 4096

typedef __attribute__((ext_vector_type(2))) unsigned int u2v;
typedef __attribute__((ext_vector_type(4))) unsigned int u4v;
typedef __attribute__((ext_vector_type(2))) __fp16 f16x2;
typedef __attribute__((ext_vector_type(2))) _Float16 F16x2;
union HU { unsigned int u; f16x2 hf; F16x2 hF; };

// ws layout (float offsets):
//   M    @ 0      : 2048*64 = 131072   (W_in @ C)
//   wtil @ 131072 : 64                 (C^T @ dense_W[:64])
//   yp   @ 131200 : 4096*64 = 262144   (per-WG dense partials)
//   hpub @ 393344 : 2 slots * 1024 packets * (u32 data, u32 tag)
// hpub needs NO init: ws poisoned 0xAA -> tag never matches 1..TT.

__global__ void esn_prep(const float* __restrict__ C,
                         const float* __restrict__ Win,
                         const float* __restrict__ dW,
                         float* __restrict__ M,
                         float* __restrict__ wtil) {
  __shared__ float s[64];
  const int b = blockIdx.x, i = threadIdx.x;
  if (b < 2048) {
    s[i] = Win[b * 64 + i];
    __syncthreads();
    float acc = 0.f;
#pragma unroll 16
    for (int d = 0; d < 64; ++d) acc += s[d] * C[d * 64 + i];
    M[b * 64 + i] = acc;
  } else {
    s[i] = dW[i];
    __syncthreads();
    float acc = 0.f;
    for (int d = 0; d < 64; ++d) acc += s[d] * C[d * 64 + i];
    wtil[i] = acc;
  }
}

// Call-free tanh: tanh(x) = 1 - 2/(exp(2x)+1)
__device__ __forceinline__ float fast_tanh(float x) {
  const float e = __builtin_amdgcn_exp2f(x * 2.8853900817779268f);
  return 1.0f - 2.0f * __builtin_amdgcn_rcpf(e + 1.0f);
}

__device__ __forceinline__ float fd(unsigned wa, unsigned ha, float c) {
  HU A, B; A.u = wa; B.u = ha;
#if __has_builtin(__builtin_amdgcn_fdot2)
  return __builtin_amdgcn_fdot2(A.hF, B.hF, c, false);
#else
  return c + (float)A.hf.x * (float)B.hf.x + (float)A.hf.y * (float)B.hf.y;
#endif
}

// 64 WGs x 1024 threads (R9 topology -- proven best). Diffs vs R9:
//  * per-wave IMMEDIATE publish (no pre-publish barrier, no LDS staging)
//  * wave0 = poller (also computes): 8x dwordx4 sweeps via two base regs
//    (13-bit signed offset limit: max +4095), incremental per-chunk commit
//    straight into shh (commit IS the repack), one step-tagged LDS flag
//    release when all 8 chunks done
//  * compute waves spin on the LDS flag with s_sleep(1) (don't starve the
//    poller's issue slots), ZERO __syncthreads per step
//  * slot-reuse safety: publishing tag t+3 requires this WG's waves passed
//    flg>=t+2, i.e. its poller saw ALL tags t+2, i.e. every WG published
//    t+2, i.e. every WG's poller consumed ALL tags t+1 -- so a tag-(t+1)
//    packet is only overwritten after all 64 pollers consumed it (same
//    invariant that protected R9's double buffer).
//  * yp: psm[4] ring, wave1 flushes step t-2 after its publish (slack proven:
//    writers concurrent with a reader at t are at t or t+1 -> slots t&3,
//    (t+1)&3, both != (t-2)&3).
__global__ __launch_bounds__(1024) void esn_recur(
    const float* __restrict__ X, const float* __restrict__ M,
    const float* __restrict__ W, const float* __restrict__ dW,
    unsigned int* __restrict__ hpub, float* __restrict__ yp) {
  extern __shared__ unsigned int smem[];
  unsigned int* w16 = smem;             // 32 rows x 1024 u32 (fp16 pairs)
  unsigned int* shh = smem + 32768;     // 2 x 1024 u32 (double-buffered h)
  float* psm = (float*)(smem + 34816);  // 4 x 16 ring
  unsigned int* flg = smem + 34880;     // 1 step-tagged flag
  const int tid = threadIdx.x;
  const int lane = tid & 63;
  const int wave = tid >> 6;
  const int b = blockIdx.x;
  const int r0 = b * 32 + wave * 2;
  const float m0 = M[r0 * 64 + lane];
  const float m1 = M[(r0 + 1) * 64 + lane];
  const float dw0 = dW[64 + r0];
  const float dw1 = dW[64 + r0 + 1];
  // one-time: stage this WG's 32 rows of W into LDS as packed fp16
  for (int i = tid; i < 32768; i += 1024) {
    const int r = i >> 10, j = i & 1023;
    const float2 w2 = *(const float2*)(W + (size_t)(b * 32 + r) * 2048 + 2 * j);
    HU hu; hu.hf = __builtin_amdgcn_cvt_pkrtz(w2.x, w2.y);
    w16[i] = hu.u;
  }
  shh[1024 + tid] = 0u;  // slot 1 = h_{-1} = 0 (read at t=0)
  if (tid == 0) *flg = 0u;
  __syncthreads();  // one-time only

  const unsigned int* wr0 = w16 + ((wave * 2) << 10);
  const unsigned int* wr1 = wr0 + 1024;
  for (int t = 0; t < TT; ++t) {
    // ---- wait until h_{t-1} is in shh slot (t+1)&1 (flag value t) ----
    if (wave != 0) {
      while (__hip_atomic_load(flg, __ATOMIC_ACQUIRE,
                               __HIP_MEMORY_SCOPE_WORKGROUP) < (unsigned)t) {
        __builtin_amdgcn_s_sleep(1);
      }
    }
    // ---- compute 2 rows from LDS ----
    const unsigned int* shr = shh + (((t + 1) & 1) << 10);
    const float xv = X[t * 64 + lane];
    float a0 = m0 * xv, a1 = m1 * xv;
#pragma unroll
    for (int j = 0; j < 4; ++j) {
      const int o = 4 * lane + 256 * j;
      const u4v hq = *(const u4v*)(shr + o);
      const u4v wq0 = *(const u4v*)(wr0 + o);
      const u4v wq1 = *(const u4v*)(wr1 + o);
#pragma unroll
      for (int k = 0; k < 4; ++k) {
        a0 = fd(wq0[k], hq[k], a0);
        a1 = fd(wq1[k], hq[k], a1);
      }
    }
#pragma unroll
    for (int off = 32; off; off >>= 1) {
      a0 += __shfl_xor(a0, off, 64);
      a1 += __shfl_xor(a1, off, 64);
    }
    const unsigned tg = (unsigned)t + 1u;
    unsigned int* slot = hpub + ((t & 1) << 11);
    if (lane == 0) {
      const float h0 = fast_tanh(a0);
      const float h1 = fast_tanh(a1);
      HU pk; pk.hf = __builtin_amdgcn_cvt_pkrtz(h0, h1);
      u2v pv; pv.x = pk.u; pv.y = tg;
      // IMMEDIATE publish -- departs the moment this wave's reduce is done
      asm volatile("global_store_dwordx2 %0, %1, off sc0 sc1"
                   :: "v"(slot + 2 * (16 * b + wave)), "v"(pv) : "memory");
      psm[(t & 3) * 16 + wave] = dw0 * h0 + dw1 * h1;
      // yp flush for step t-2 (ring slack proven in header comment)
      if (wave == 1 && t >= 2) {
        float s = 0.f;
#pragma unroll
        for (int wv = 0; wv < 16; ++wv) s += psm[((t - 2) & 3) * 16 + wv];
        yp[(t - 2) * 64 + b] = s;
      }
    }
    // ---- wave0: poll slot (t&1) for tags t+1, commit h_t, release flag ----
    if (wave == 0 && t + 1 < TT) {
      unsigned int* dsh = shh + ((t & 1) << 10);
      const unsigned int* p0 = slot + 4 * lane;          // chunks 0-3
      const unsigned int* p1 = slot + 1024 + 4 * lane;   // chunks 4-7
      unsigned done = 0u;
#define COMMIT(c, Q)                                                        \
      if (!((done >> (c)) & 1u) && __all((Q).y == tg && (Q).w == tg)) {     \
        *(uint2*)(dsh + 128 * (c) + 2 * lane) = make_uint2((Q).x, (Q).z);   \
        done |= 1u << (c);                                                  \
      }
      for (;;) {
        u4v q0, q1, q2, q3, q4, q5, q6, q7;
        asm volatile(
            "global_load_dwordx4 %0, %8, off sc0 sc1\n\t"
            "global_load_dwordx4 %1, %8, off offset:1024 sc0 sc1\n\t"
            "global_load_dwordx4 %2, %8, off offset:2048 sc0 sc1\n\t"
            "global_load_dwordx4 %3, %8, off offset:3072 sc0 sc1\n\t"
            "global_load_dwordx4 %4, %9, off sc0 sc1\n\t"
            "global_load_dwordx4 %5, %9, off offset:1024 sc0 sc1\n\t"
            "global_load_dwordx4 %6, %9, off offset:2048 sc0 sc1\n\t"
            "global_load_dwordx4 %7, %9, off offset:3072 sc0 sc1\n\t"
            "s_waitcnt vmcnt(0)"
            : "=&v"(q0), "=&v"(q1), "=&v"(q2), "=&v"(q3),
              "=&v"(q4), "=&v"(q5), "=&v"(q6), "=&v"(q7)
            : "v"(p0), "v"(p1)
            : "memory");
        const unsigned before = done;
        COMMIT(0, q0) COMMIT(1, q1) COMMIT(2, q2) COMMIT(3, q3)
        COMMIT(4, q4) COMMIT(5, q5) COMMIT(6, q6) COMMIT(7, q7)
        if (done == 0xFFu) break;
        if (done == before) __builtin_amdgcn_s_sleep(1);
      }
#undef COMMIT
      if (lane == 0)
        __hip_atomic_store(flg, tg, __ATOMIC_RELEASE,
                           __HIP_MEMORY_SCOPE_WORKGROUP);
    }
  }
  // final yp flushes (steps TT-2, TT-1)
  __syncthreads();
  if (tid == 0) {
    float s2 = 0.f, s1 = 0.f;
#pragma unroll
    for (int wv = 0; wv < 16; ++wv) {
      s2 += psm[((TT - 2) & 3) * 16 + wv];
      s1 += psm[((TT - 1) & 3) * 16 + wv];
    }
    yp[(TT - 2) * 64 + b] = s2;
    yp[(TT - 1) * 64 + b] = s1;
  }
}

__global__ void esn_out(const float* __restrict__ X,
                        const float* __restrict__ wtil,
                        const float* __restrict__ yp,
                        const float* __restrict__ bptr,
                        float* __restrict__ out) {
  const int tid = threadIdx.x;
  const int lane = tid & 63;
  const int wave = tid >> 6;
  const int t = blockIdx.x * 4 + wave;
  float v = wtil[lane] * X[t * 64 + lane] + yp[t * 64 + lane];
#pragma unroll
  for (int off = 32; off; off >>= 1) v += __shfl_xor(v, off, 64);
  if (lane == 0) out[t] = v + bptr[0];
}

#define ESN_LDS_BYTES 139524  // (32768 + 2048 + 64 + 1) * 4

struct EsnInit {
  EsnInit() {
    (void)hipFuncSetAttribute(reinterpret_cast<const void*>(&esn_recur),
                              hipFuncAttributeMaxDynamicSharedMemorySize,
                              ESN_LDS_BYTES);
  }
};
static EsnInit g_esn_init;

extern "C" void kernel_launch(void* const* d_in, const int* in_sizes, int n_in,
                              void* d_out, int out_size, void* d_ws, size_t ws_size,
                              hipStream_t stream) {
  const float* X   = (const float*)d_in[0];
  const float* C   = (const float*)d_in[1];
  const float* Win = (const float*)d_in[2];
  const float* W   = (const float*)d_in[3];
  const float* dW  = (const float*)d_in[4];
  const float* db  = (const float*)d_in[5];
  float* ws   = (float*)d_ws;
  float* M    = ws;
  float* wtil = ws + 131072;
  float* yp   = ws + 131200;
  unsigned int* hpub = (unsigned int*)(ws + 393344);

  esn_prep<<<2049, 64, 0, stream>>>(C, Win, dW, M, wtil);

  void* args[] = {(void*)&X, (void*)&M, (void*)&W, (void*)&dW,
                  (void*)&hpub, (void*)&yp};
  (void)hipLaunchCooperativeKernel(reinterpret_cast<void*>(&esn_recur), dim3(64),
                                   dim3(1024), args, ESN_LDS_BYTES, stream);

  esn_out<<<1024, 256, 0, stream>>>(X, wtil, yp, db, (float*)d_out);
}